// Round 9
// baseline (5166.793 us; speedup 1.0000x reference)
//
#include <hip/hip_runtime.h>

typedef __attribute__((ext_vector_type(8))) short short8;
typedef __attribute__((ext_vector_type(4))) float f32x4;
typedef __attribute__((ext_vector_type(4))) unsigned int u32x4;

#define TT 512
#define HD 1024
#define BD 64
#define NWG 256

union FRAG { u32x4 d; short8 s; };

// ---- fp32 -> bf16 round-to-nearest-even ----
__device__ __forceinline__ unsigned short f2bf(float f) {
  unsigned u = __float_as_uint(f);
  u += 0x7fffu + ((u >> 16) & 1u);
  return (unsigned short)(u >> 16);
}

// ============================================================================
// Prep: inputs [B][T][512] fp32 -> XT bf16 in MFMA A-fragment order.
// ============================================================================
__global__ void prep_xt(const float* __restrict__ x, short8* __restrict__ XT) {
  const int bid = blockIdx.x;  // b*512 + t
  const int b = bid >> 9;
  const int t = bid & 511;
  const int tid = threadIdx.x;  // k-octet
  const float* src = x + ((size_t)(b * TT + t)) * 512 + tid * 8;
  const f32x4* s4 = (const f32x4*)src;
  f32x4 lo = s4[0], hi = s4[1];
  short8 o;
#pragma unroll
  for (int j = 0; j < 4; ++j) {
    o[j] = (short)f2bf(lo[j]);
    o[4 + j] = (short)f2bf(hi[j]);
  }
  const int bt = b >> 4, m = b & 15, ks = tid >> 2, q = tid & 3;
  XT[(((size_t)bt * TT + t) * 16 + ks) * 64 + q * 16 + m] = o;
}

// h-state: 2 parities x [4 bt][32 ks][64 lane][16B] = 2 x 131072 B
#define PARB ((size_t)131072)

// Flag spin ONLY (R5's proven 2-deep pipelined structure; loads+waits in one
// asm block, rule-18-safe). Exits with vmcnt fully drained (a dangling
// outstanding load would corrupt whatever reuses the output VGPRs).
#define WAIT_FLAGS()                                                      \
  asm volatile(                                                           \
      "global_load_dword %0, %2, off sc0 sc1\n\t"                         \
      "s_sleep 4\n\t"                                                     \
      "global_load_dword %1, %2, off sc0 sc1\n\t"                         \
      "1:\n\t"                                                            \
      "s_waitcnt vmcnt(1)\n\t"                                            \
      "v_cmp_gt_u32 vcc, %3, %0\n\t"                                      \
      "s_cbranch_vccz 2f\n\t"                                             \
      "global_load_dword %0, %2, off sc0 sc1\n\t"                         \
      "s_waitcnt vmcnt(1)\n\t"                                            \
      "v_cmp_gt_u32 vcc, %3, %1\n\t"                                      \
      "s_cbranch_vccz 2f\n\t"                                             \
      "global_load_dword %1, %2, off sc0 sc1\n\t"                         \
      "s_branch 1b\n\t"                                                   \
      "2:\n\t"                                                            \
      "s_waitcnt vmcnt(0)"                                                \
      : "=&v"(f0s), "=&v"(f1s)                                            \
      : "v"(hint_p), "v"(tt_)                                             \
      : "vcc", "memory")

// ============================================================================
// Persistent fused GRU scan. 256 WGs = 4 groups (bt) x 64 (ct).
//
// Protocol = R5's measured-best scheme with ONE change: the h DATA loads go
// through the normal cached path (L1/L2) instead of the coherent fabric.
//   producer: paired 4B h stores (agent-scope relaxed = sc0 sc1 write-
//             through, visible at LLC) -> s_waitcnt vmcnt(0) ack -> per-wave
//             flag store. Unchanged from R5.
//   consumer: coherent flag spin (asm above) -> ACQUIRE FENCE (agent) ->
//             PLAIN cached loads of the 8x16B h fragments.
// Why: each group's 32KB h slice is read by all 64 WGs -> 8MB/step of
// sc0sc1 reads that ALL hit the LLC (fabric serialization was the dominant
// residual cost). Cached loads let each XCD's L2 serve its ~32 resident
// consumers: ~16x less LLC traffic. Correctness: flag==t (acquired) implies
// data at LLC (producer acked before flag); the acquire fence invalidates
// L1/L2 so no stale clean line can satisfy the subsequent loads; consumers
// never dirty h lines (only producers write, write-through). Safety
// induction on buffer reuse identical to R5.
// LDS: wh 96KB + wx 48KB + red 16KB = 160KB exactly -> 1 WG/CU, grid=256 CUs.
// ============================================================================
__global__ __launch_bounds__(256, 1) void gru_main(
    const float* __restrict__ Wxr, const float* __restrict__ bxr,
    const float* __restrict__ Whr,
    const float* __restrict__ Wxz, const float* __restrict__ bxz,
    const float* __restrict__ Whz,
    const float* __restrict__ Wxn, const float* __restrict__ bxn,
    const float* __restrict__ Whn,
    const short8* __restrict__ XT, char* __restrict__ HFc,
    unsigned* __restrict__ flags, float* __restrict__ out) {
  extern __shared__ char lds[];
  short8* wh = (short8*)lds;             // [3][32][64]
  short8* wx = (short8*)(lds + 98304);   // [3][16][64]
  float* red = (float*)(lds + 147456);   // [4][4][64][4]

  const int wg = blockIdx.x;
  const int bt = wg & 3;   // XCD-aligned batch group
  const int ct = wg >> 2;  // 0..63 group member
  const int c0 = ct << 4;
  const int tid = threadIdx.x;
  const int wv = tid >> 6;
  const int lane = tid & 63;

  // ---- stage Wh (B-fragment order)
  for (int idx = tid; idx < 3 * 32 * 64; idx += 256) {
    const int g = idx >> 11, rem = idx & 2047, ks = rem >> 6, ln = rem & 63;
    const float* W = (g == 0) ? Whr : (g == 1) ? Whz : Whn;
    const float* src = W + (size_t)(c0 + (ln & 15)) * HD + ks * 32 + (ln >> 4) * 8;
    short8 v;
#pragma unroll
    for (int j = 0; j < 8; ++j) v[j] = (short)f2bf(src[j]);
    wh[idx] = v;
  }
  // ---- stage Wx
  for (int idx = tid; idx < 3 * 16 * 64; idx += 256) {
    const int g = idx >> 10, rem = idx & 1023, ks = rem >> 6, ln = rem & 63;
    const float* W = (g == 0) ? Wxr : (g == 1) ? Wxz : Wxn;
    const float* src = W + (size_t)(c0 + (ln & 15)) * 512 + ks * 32 + (ln >> 4) * 8;
    short8 v;
#pragma unroll
    for (int j = 0; j < 8; ++j) v[j] = (short)f2bf(src[j]);
    wx[idx] = v;
  }
  __syncthreads();

  // ---- per-thread output ownership
  const int c_off = tid & 15, b_off = tid >> 4;
  const int c = c0 + c_off;
  const int b = (bt << 4) + b_off;
  const float br_ = bxr[c], bz_ = bxz[c], bn_ = bxn[c];
  float h_old = 0.f;

  const int rl = ((b_off >> 2) << 4) + c_off;
  const int rr = b_off & 3;

  // producer h byte offset (even-c threads store the (c,c+1) dword pair)
  const size_t prod_byte =
      ((size_t)((bt * 32 + (c >> 5)) * 64 + ((c >> 3) & 3) * 16 + b_off)) * 16 +
      (size_t)(c & 7) * 2;
  // producer flag slot
  unsigned* my_flag = flags + bt * 256 + ct * 4 + wv;
  // consumer: wave wv needs producers ct' in [wv*16,(wv+1)*16), all 4 waves
  // -> 64 contiguous flag dwords, 1 per lane
  const unsigned* hint_p = flags + bt * 256 + (wv << 6) + lane;
  // consumer h base: this wave's 8-ks input slice, 16B per (ks,lane)
  const char* cons_base =
      HFc + ((size_t)(bt * 32 + (wv << 3)) * 64 + lane) * 16;

  float* out_hlast = out;
  float* out_hidden = out + BD * HD;

  for (int t = 0; t < TT; ++t) {
    const char* cb = cons_base + (size_t)(t & 1) * PARB;

    // ---- x fragments (global; hidden under step slack)
    const short8* xrd = XT + (((size_t)bt * TT + t) * 16 + (wv << 2)) * 64 + lane;
    short8 xa[4];
#pragma unroll
    for (int kk = 0; kk < 4; ++kk) xa[kk] = xrd[kk * 64];

    // ---- prefetch wh B-fragments into VGPRs (h-MFMAs fire the moment h
    // data lands; R5-proven)
    short8 whf0[8], whf1[8], whf2[8];
#pragma unroll
    for (int kk = 0; kk < 8; ++kk) {
      whf0[kk] = wh[(0 * 32 + (wv << 3) + kk) * 64 + lane];
      whf1[kk] = wh[(1 * 32 + (wv << 3) + kk) * 64 + lane];
      whf2[kk] = wh[(2 * 32 + (wv << 3) + kk) * 64 + lane];
    }

    f32x4 aR = {0.f, 0.f, 0.f, 0.f};
    f32x4 aZ = {0.f, 0.f, 0.f, 0.f};
    f32x4 aNh = {0.f, 0.f, 0.f, 0.f};
    f32x4 aNx = {0.f, 0.f, 0.f, 0.f};
#pragma unroll
    for (int kk = 0; kk < 4; ++kk) {
      const int ks = (wv << 2) + kk;
      aR = __builtin_amdgcn_mfma_f32_16x16x32_bf16(xa[kk], wx[(0 * 16 + ks) * 64 + lane], aR, 0, 0, 0);
      aZ = __builtin_amdgcn_mfma_f32_16x16x32_bf16(xa[kk], wx[(1 * 16 + ks) * 64 + lane], aZ, 0, 0, 0);
      aNx = __builtin_amdgcn_mfma_f32_16x16x32_bf16(xa[kk], wx[(2 * 16 + ks) * 64 + lane], aNx, 0, 0, 0);
    }

    // ---- coherent flag spin (R5 structure)
    unsigned f0s, f1s;
    const unsigned tt_ = (unsigned)t;
    WAIT_FLAGS();

    // ---- acquire fence: invalidate L1/L2 so cached loads below observe
    // everything the flags certify is at the LLC
    __builtin_amdgcn_fence(__ATOMIC_ACQUIRE, "agent");

    // ---- h fragment loads via the NORMAL cached path (L2 serves the
    // intra-XCD broadcast; compiler schedules loads + waitcnts)
    u32x4 H[8];
    {
      const u32x4* hp = (const u32x4*)cb;
#pragma unroll
      for (int kk = 0; kk < 8; ++kk) H[kk] = hp[(size_t)kk * 64];
    }

    // ---- h MFMAs (prefetched B-frags)
#pragma unroll
    for (int kk = 0; kk < 8; ++kk) {
      FRAG f;
      f.d = H[kk];
      aR = __builtin_amdgcn_mfma_f32_16x16x32_bf16(f.s, whf0[kk], aR, 0, 0, 0);
      aZ = __builtin_amdgcn_mfma_f32_16x16x32_bf16(f.s, whf1[kk], aZ, 0, 0, 0);
      aNh = __builtin_amdgcn_mfma_f32_16x16x32_bf16(f.s, whf2[kk], aNh, 0, 0, 0);
    }

    // ---- single-round cross-wave K-reduction
    {
      f32x4* r4 = (f32x4*)red;
      r4[(0 * 4 + wv) * 64 + lane] = aR;
      r4[(1 * 4 + wv) * 64 + lane] = aZ;
      r4[(2 * 4 + wv) * 64 + lane] = aNh;
      r4[(3 * 4 + wv) * 64 + lane] = aNx;
    }
    __syncthreads();
    float sR = 0.f, sZ = 0.f, sNh = 0.f, sNx = 0.f;
#pragma unroll
    for (int v = 0; v < 4; ++v) {
      sR += red[((0 * 4 + v) * 64 + rl) * 4 + rr];
      sZ += red[((1 * 4 + v) * 64 + rl) * 4 + rr];
      sNh += red[((2 * 4 + v) * 64 + rl) * 4 + rr];
      sNx += red[((3 * 4 + v) * 64 + rl) * 4 + rr];
    }
    // red is rewritten next iteration; the narrowed polls don't cover own-WG
    // waves, so fence the buffer explicitly (also merges the 4 waves' flag
    // knowledge -> WG-level certificate for the buffer-reuse induction).
    __syncthreads();

    // ---- gates
    const float r = 1.f / (1.f + __expf(-(sR + br_)));
    const float z = 1.f / (1.f + __expf(-(sZ + bz_)));
    float pre_n = sNx + bn_ + r * sNh;
    pre_n = fminf(fmaxf(pre_n, -30.f), 30.f);
    const float e2 = __expf(2.f * pre_n);
    const float n = (e2 - 1.f) / (e2 + 1.f);
    const float hn = (1.f - z) * n + z * h_old;
    h_old = hn;

    // ---- paired h store (4B dword), vmcnt(0) ack, then flag (R5 verbatim)
    const unsigned hb = f2bf(hn);
    const unsigned hb_hi = (unsigned)__shfl_down((int)hb, 1);

    if (t < TT - 1) {
      if (!(c_off & 1)) {
        __hip_atomic_store(
            (unsigned*)(HFc + (size_t)((t + 1) & 1) * PARB + prod_byte),
            hb | (hb_hi << 16), __ATOMIC_RELAXED, __HIP_MEMORY_SCOPE_AGENT);
      }
      asm volatile("s_waitcnt vmcnt(0)" ::: "memory");  // data acked at LLC
      if (lane == 0) {
        __hip_atomic_store(my_flag, (unsigned)(t + 1), __ATOMIC_RELAXED,
                           __HIP_MEMORY_SCOPE_AGENT);
      }
      // out store drains under the next step (off the critical path)
      out_hidden[((size_t)b * TT + t) * HD + c] = hn;
    } else {
      out_hidden[((size_t)b * TT + t) * HD + c] = hn;
      out_hlast[(size_t)b * HD + c] = hn;
    }
  }
}

// ============================================================================
extern "C" void kernel_launch(void* const* d_in, const int* in_sizes, int n_in,
                              void* d_out, int out_size, void* d_ws, size_t ws_size,
                              hipStream_t stream) {
  const float* inputs = (const float*)d_in[0];
  const float* Wxr = (const float*)d_in[1];
  const float* bxr = (const float*)d_in[2];
  const float* Whr = (const float*)d_in[3];
  const float* Wxz = (const float*)d_in[4];
  const float* bxz = (const float*)d_in[5];
  const float* Whz = (const float*)d_in[6];
  const float* Wxn = (const float*)d_in[7];
  const float* bxn = (const float*)d_in[8];
  const float* Whn = (const float*)d_in[9];
  float* out = (float*)d_out;

  char* ws = (char*)d_ws;
  short8* XT = (short8*)ws;                              // 33,554,432 B
  char* HF = ws + 33554432;                              //    262,144 B
  unsigned* flags = (unsigned*)(ws + 33554432 + 262144); //      4,096 B

  // h0 = 0 (both parities) + flags = 0 (t=0 check: 0 > 0 false -> pass).
  hipMemsetAsync(HF, 0, 262144 + 4096, stream);
  prep_xt<<<dim3(64 * 512), dim3(64), 0, stream>>>(inputs, XT);

  (void)hipFuncSetAttribute((const void*)gru_main,
                            hipFuncAttributeMaxDynamicSharedMemorySize, 163840);
  gru_main<<<dim3(NWG), dim3(256), 163840, stream>>>(
      Wxr, bxr, Whr, Wxz, bxz, Whz, Wxn, bxn, Whn, XT, HF, flags, out);
}